// Round 1
// baseline (1213.688 us; speedup 1.0000x reference)
//
#include <hip/hip_runtime.h>

#define DF 128     // feature dim
#define BM 128     // GEMM row tile
#define KC 32      // GEMM k-chunk
#define KTOT 256   // concatenated K: [agg | feat]

// ---------------------------------------------------------------------------
// Index dtype detection: if the src array is int64 (little-endian, values
// < 2^31), every odd int32 slot is zero. If we find any nonzero odd slot,
// the data is int32 -> set *flag32 = 1. (flag32 pre-zeroed by memset.)
// ---------------------------------------------------------------------------
__global__ __launch_bounds__(128) void detect_idx_kernel(
    const int* __restrict__ idx32, int n, int* __restrict__ flag32)
{
    int t = threadIdx.x;
    int found = 0;
    for (int i = t; i < 2048 && i < n; i += 128) {
        if (idx32[2 * i + 1] != 0) found = 1;
    }
    if (__any(found) && (t & 63) == 0) atomicOr(flag32, 1);
}

// ---------------------------------------------------------------------------
// Scatter-aggregate: agg[dst[e]] += feat[src[e]], 32 lanes per edge,
// float4 per lane, hardware fp32 atomics.
// ---------------------------------------------------------------------------
__global__ __launch_bounds__(256) void scatter_kernel(
    const float* __restrict__ feat,
    const void* __restrict__ src, const void* __restrict__ dst,
    float* __restrict__ agg, int nE, const int* __restrict__ flag32)
{
    int gid = blockIdx.x * 256 + threadIdx.x;
    int e = gid >> 5;
    if (e >= nE) return;
    int lane = gid & 31;

    long long s, d;
    if (*flag32 == 0) {  // int64 indices
        s = ((const long long*)src)[e];
        d = ((const long long*)dst)[e];
    } else {             // int32 indices
        s = ((const int*)src)[e];
        d = ((const int*)dst)[e];
    }

    const float4 v = *reinterpret_cast<const float4*>(feat + s * DF + lane * 4);
    float* p = agg + d * DF + lane * 4;
    unsafeAtomicAdd(p + 0, v.x);
    unsafeAtomicAdd(p + 1, v.y);
    unsafeAtomicAdd(p + 2, v.z);
    unsafeAtomicAdd(p + 3, v.w);
}

// ---------------------------------------------------------------------------
// Fused GEMM: out = [agg | feat] @ [W_neigh ; W_self] + b_neigh
// M x 256 x 128, fp32 vector ALU. 128-row tile per block, 8x8 per thread.
// ---------------------------------------------------------------------------
__global__ __launch_bounds__(256) void gemm_kernel(
    const float* __restrict__ agg, const float* __restrict__ feat,
    const float* __restrict__ Wn, const float* __restrict__ Wsf,
    const float* __restrict__ bias, float* __restrict__ out, int M)
{
    __shared__ float As[KC][BM + 8];   // transposed: As[k][row], pad avoids bank conflicts
    __shared__ float Bs[KC][DF];       // Bs[k][col]

    const int t = threadIdx.x;
    const int block_row = blockIdx.x * BM;
    const int ct = t & 15;             // 16 col groups x 8 cols
    const int rt = t >> 4;             // 16 row groups x 8 rows
    const int c0 = ct * 8;
    const int r0 = rt * 8;

    float acc[8][8];
#pragma unroll
    for (int i = 0; i < 8; i++)
#pragma unroll
        for (int j = 0; j < 8; j++) acc[i][j] = 0.0f;

    float bv[8];
#pragma unroll
    for (int j = 0; j < 8; j++) bv[j] = bias[c0 + j];

    // staging indices
    const int arow  = t >> 1;          // 0..127 (2 threads per row)
    const int akoff = (t & 1) * 16;    // 0 or 16
    const int brow  = t >> 3;          // 0..31
    const int bcol  = (t & 7) * 16;    // 0..112

    for (int kc = 0; kc < KTOT; kc += KC) {
        const float* Asrc = (kc < DF) ? agg : feat;
        const float* Bsrc = (kc < DF) ? Wn  : Wsf;
        const int kb = kc & (DF - 1);

        // --- stage A chunk (transposed into LDS) ---
        {
            const int grow = block_row + arow;
            float4 v[4];
            if (grow < M) {
                const float4* p = reinterpret_cast<const float4*>(
                    Asrc + (size_t)grow * DF + kb + akoff);
#pragma unroll
                for (int i = 0; i < 4; i++) v[i] = p[i];
            } else {
#pragma unroll
                for (int i = 0; i < 4; i++) v[i] = make_float4(0.f, 0.f, 0.f, 0.f);
            }
#pragma unroll
            for (int i = 0; i < 4; i++) {
                As[akoff + i * 4 + 0][arow] = v[i].x;
                As[akoff + i * 4 + 1][arow] = v[i].y;
                As[akoff + i * 4 + 2][arow] = v[i].z;
                As[akoff + i * 4 + 3][arow] = v[i].w;
            }
        }
        // --- stage B chunk (direct copy) ---
        {
            const float4* p = reinterpret_cast<const float4*>(
                Bsrc + (size_t)(kb + brow) * DF + bcol);
#pragma unroll
            for (int i = 0; i < 4; i++)
                *reinterpret_cast<float4*>(&Bs[brow][bcol + i * 4]) = p[i];
        }
        __syncthreads();

#pragma unroll 8
        for (int k = 0; k < KC; k++) {
            float a[8], w[8];
            *reinterpret_cast<float4*>(&a[0]) = *reinterpret_cast<const float4*>(&As[k][r0]);
            *reinterpret_cast<float4*>(&a[4]) = *reinterpret_cast<const float4*>(&As[k][r0 + 4]);
            *reinterpret_cast<float4*>(&w[0]) = *reinterpret_cast<const float4*>(&Bs[k][c0]);
            *reinterpret_cast<float4*>(&w[4]) = *reinterpret_cast<const float4*>(&Bs[k][c0 + 4]);
#pragma unroll
            for (int i = 0; i < 8; i++)
#pragma unroll
                for (int j = 0; j < 8; j++)
                    acc[i][j] = fmaf(a[i], w[j], acc[i][j]);
        }
        __syncthreads();
    }

    // --- epilogue: add bias, store ---
#pragma unroll
    for (int i = 0; i < 8; i++) {
        const int grow = block_row + r0 + i;
        if (grow < M) {
            float* po = out + (size_t)grow * DF + c0;
            float4 o0, o1;
            o0.x = acc[i][0] + bv[0]; o0.y = acc[i][1] + bv[1];
            o0.z = acc[i][2] + bv[2]; o0.w = acc[i][3] + bv[3];
            o1.x = acc[i][4] + bv[4]; o1.y = acc[i][5] + bv[5];
            o1.z = acc[i][6] + bv[6]; o1.w = acc[i][7] + bv[7];
            *reinterpret_cast<float4*>(po)     = o0;
            *reinterpret_cast<float4*>(po + 4) = o1;
        }
    }
}

extern "C" void kernel_launch(void* const* d_in, const int* in_sizes, int n_in,
                              void* d_out, int out_size, void* d_ws, size_t ws_size,
                              hipStream_t stream) {
    const float* feat = (const float*)d_in[0];
    const void*  src  = d_in[1];
    const void*  dst  = d_in[2];
    const float* Wn   = (const float*)d_in[3];
    const float* bias = (const float*)d_in[4];
    const float* Wsf  = (const float*)d_in[5];
    float* out = (float*)d_out;

    const int M  = in_sizes[0] / DF;   // 100000
    const int nE = in_sizes[1];        // 600000

    int*   flag = (int*)d_ws;                          // 256 B header
    float* agg  = (float*)((char*)d_ws + 256);         // [M, DF] fp32

    const size_t zero_bytes = 256 + (size_t)M * DF * sizeof(float);
    hipMemsetAsync(d_ws, 0, zero_bytes, stream);

    detect_idx_kernel<<<1, 128, 0, stream>>>((const int*)src, nE, flag);

    const int sblocks = (int)(((long long)nE * 32 + 255) / 256);
    scatter_kernel<<<sblocks, 256, 0, stream>>>(feat, src, dst, agg, nE, flag);

    const int gblocks = (M + BM - 1) / BM;
    gemm_kernel<<<gblocks, 256, 0, stream>>>(agg, feat, Wn, Wsf, bias, out, M);
}

// Round 2
// 304.040 us; speedup vs baseline: 3.9919x; 3.9919x over previous
//
#include <hip/hip_runtime.h>

#define DF 128     // feature dim
#define BM 128     // GEMM row tile
#define KC 32      // GEMM k-chunk
#define KTOT 256   // concatenated K: [agg | feat]
#define CAP 32     // bucket capacity per node (fallback atomics past this)

// ---------------------------------------------------------------------------
// Index dtype detection: if the src array is int64 (little-endian, values
// < 2^31), every odd int32 slot is zero. If we find any nonzero odd slot,
// the data is int32 -> set *flag32 = 1. (flag32 pre-zeroed by memset.)
// ---------------------------------------------------------------------------
__global__ __launch_bounds__(128) void detect_idx_kernel(
    const int* __restrict__ idx32, int n, int* __restrict__ flag32)
{
    int t = threadIdx.x;
    int found = 0;
    for (int i = t; i < 2048 && i < n; i += 128) {
        if (idx32[2 * i + 1] != 0) found = 1;
    }
    if (__any(found) && (t & 63) == 0) atomicOr(flag32, 1);
}

__device__ __forceinline__ void load_edge(const void* src, const void* dst,
                                          int e, int is32, long long& s, long long& d)
{
    if (is32) {
        s = ((const int*)src)[e];
        d = ((const int*)dst)[e];
    } else {
        s = ((const long long*)src)[e];
        d = ((const long long*)dst)[e];
    }
}

// ---------------------------------------------------------------------------
// Placement: one thread per edge. pos = count[dst]++; bucket[dst*CAP+pos]=src.
// Overflow (pos >= CAP, astronomically rare for E/N=6) falls back to direct
// fp32 atomics into agg -- correctness guaranteed for any degree distribution.
// ---------------------------------------------------------------------------
__global__ __launch_bounds__(256) void placement_kernel(
    const float* __restrict__ feat,
    const void* __restrict__ src, const void* __restrict__ dst,
    int* __restrict__ counts, int* __restrict__ buckets,
    float* __restrict__ agg, int nE, const int* __restrict__ flag32)
{
    int e = blockIdx.x * 256 + threadIdx.x;
    if (e >= nE) return;
    long long s, d;
    load_edge(src, dst, e, *flag32, s, d);

    int pos = atomicAdd(&counts[d], 1);
    if (pos < CAP) {
        buckets[(size_t)d * CAP + pos] = (int)s;
    } else {
        const float* fr = feat + (size_t)s * DF;
        float* ar = agg + (size_t)d * DF;
        for (int i = 0; i < DF; i++) unsafeAtomicAdd(ar + i, fr[i]);
    }
}

// ---------------------------------------------------------------------------
// Gather: 32 lanes per node, float4 per lane. agg[node] += sum of bucketed
// neighbor rows. No atomics; agg written exactly once (plus rare fallback
// contributions already present from placement_kernel).
// ---------------------------------------------------------------------------
__global__ __launch_bounds__(256) void gather_kernel(
    const float* __restrict__ feat,
    const int* __restrict__ counts, const int* __restrict__ buckets,
    float* __restrict__ agg, int M)
{
    int gid = blockIdx.x * 256 + threadIdx.x;
    int node = gid >> 5;
    if (node >= M) return;
    int lane = gid & 31;

    int deg = counts[node];
    if (deg > CAP) deg = CAP;
    const int* b = buckets + (size_t)node * CAP;

    float* ap = agg + (size_t)node * DF + lane * 4;
    float4 acc = *reinterpret_cast<const float4*>(ap);

    for (int e = 0; e < deg; e++) {
        int s = b[e];
        const float4 v = *reinterpret_cast<const float4*>(
            feat + (size_t)s * DF + lane * 4);
        acc.x += v.x; acc.y += v.y; acc.z += v.z; acc.w += v.w;
    }
    *reinterpret_cast<float4*>(ap) = acc;
}

// ---------------------------------------------------------------------------
// Fallback scatter (only if ws_size too small for buckets): fp32 atomics.
// ---------------------------------------------------------------------------
__global__ __launch_bounds__(256) void scatter_kernel(
    const float* __restrict__ feat,
    const void* __restrict__ src, const void* __restrict__ dst,
    float* __restrict__ agg, int nE, const int* __restrict__ flag32)
{
    int gid = blockIdx.x * 256 + threadIdx.x;
    int e = gid >> 5;
    if (e >= nE) return;
    int lane = gid & 31;
    long long s, d;
    load_edge(src, dst, e, *flag32, s, d);
    const float4 v = *reinterpret_cast<const float4*>(feat + s * DF + lane * 4);
    float* p = agg + d * DF + lane * 4;
    unsafeAtomicAdd(p + 0, v.x);
    unsafeAtomicAdd(p + 1, v.y);
    unsafeAtomicAdd(p + 2, v.z);
    unsafeAtomicAdd(p + 3, v.w);
}

// ---------------------------------------------------------------------------
// Fused GEMM: out = [agg | feat] @ [W_neigh ; W_self] + b_neigh
// M x 256 x 128, fp32 vector ALU. 128-row tile per block, 8x8 per thread.
// ---------------------------------------------------------------------------
__global__ __launch_bounds__(256) void gemm_kernel(
    const float* __restrict__ agg, const float* __restrict__ feat,
    const float* __restrict__ Wn, const float* __restrict__ Wsf,
    const float* __restrict__ bias, float* __restrict__ out, int M)
{
    __shared__ float As[KC][BM + 8];   // transposed: As[k][row]
    __shared__ float Bs[KC][DF];       // Bs[k][col]

    const int t = threadIdx.x;
    const int block_row = blockIdx.x * BM;
    const int ct = t & 15;
    const int rt = t >> 4;
    const int c0 = ct * 8;
    const int r0 = rt * 8;

    float acc[8][8];
#pragma unroll
    for (int i = 0; i < 8; i++)
#pragma unroll
        for (int j = 0; j < 8; j++) acc[i][j] = 0.0f;

    float bv[8];
#pragma unroll
    for (int j = 0; j < 8; j++) bv[j] = bias[c0 + j];

    const int arow  = t >> 1;
    const int akoff = (t & 1) * 16;
    const int brow  = t >> 3;
    const int bcol  = (t & 7) * 16;

    for (int kc = 0; kc < KTOT; kc += KC) {
        const float* Asrc = (kc < DF) ? agg : feat;
        const float* Bsrc = (kc < DF) ? Wn  : Wsf;
        const int kb = kc & (DF - 1);

        {
            const int grow = block_row + arow;
            float4 v[4];
            if (grow < M) {
                const float4* p = reinterpret_cast<const float4*>(
                    Asrc + (size_t)grow * DF + kb + akoff);
#pragma unroll
                for (int i = 0; i < 4; i++) v[i] = p[i];
            } else {
#pragma unroll
                for (int i = 0; i < 4; i++) v[i] = make_float4(0.f, 0.f, 0.f, 0.f);
            }
#pragma unroll
            for (int i = 0; i < 4; i++) {
                As[akoff + i * 4 + 0][arow] = v[i].x;
                As[akoff + i * 4 + 1][arow] = v[i].y;
                As[akoff + i * 4 + 2][arow] = v[i].z;
                As[akoff + i * 4 + 3][arow] = v[i].w;
            }
        }
        {
            const float4* p = reinterpret_cast<const float4*>(
                Bsrc + (size_t)(kb + brow) * DF + bcol);
#pragma unroll
            for (int i = 0; i < 4; i++)
                *reinterpret_cast<float4*>(&Bs[brow][bcol + i * 4]) = p[i];
        }
        __syncthreads();

#pragma unroll 8
        for (int k = 0; k < KC; k++) {
            float a[8], w[8];
            *reinterpret_cast<float4*>(&a[0]) = *reinterpret_cast<const float4*>(&As[k][r0]);
            *reinterpret_cast<float4*>(&a[4]) = *reinterpret_cast<const float4*>(&As[k][r0 + 4]);
            *reinterpret_cast<float4*>(&w[0]) = *reinterpret_cast<const float4*>(&Bs[k][c0]);
            *reinterpret_cast<float4*>(&w[4]) = *reinterpret_cast<const float4*>(&Bs[k][c0 + 4]);
#pragma unroll
            for (int i = 0; i < 8; i++)
#pragma unroll
                for (int j = 0; j < 8; j++)
                    acc[i][j] = fmaf(a[i], w[j], acc[i][j]);
        }
        __syncthreads();
    }

#pragma unroll
    for (int i = 0; i < 8; i++) {
        const int grow = block_row + r0 + i;
        if (grow < M) {
            float* po = out + (size_t)grow * DF + c0;
            float4 o0, o1;
            o0.x = acc[i][0] + bv[0]; o0.y = acc[i][1] + bv[1];
            o0.z = acc[i][2] + bv[2]; o0.w = acc[i][3] + bv[3];
            o1.x = acc[i][4] + bv[4]; o1.y = acc[i][5] + bv[5];
            o1.z = acc[i][6] + bv[6]; o1.w = acc[i][7] + bv[7];
            *reinterpret_cast<float4*>(po)     = o0;
            *reinterpret_cast<float4*>(po + 4) = o1;
        }
    }
}

extern "C" void kernel_launch(void* const* d_in, const int* in_sizes, int n_in,
                              void* d_out, int out_size, void* d_ws, size_t ws_size,
                              hipStream_t stream) {
    const float* feat = (const float*)d_in[0];
    const void*  src  = d_in[1];
    const void*  dst  = d_in[2];
    const float* Wn   = (const float*)d_in[3];
    const float* bias = (const float*)d_in[4];
    const float* Wsf  = (const float*)d_in[5];
    float* out = (float*)d_out;

    const int M  = in_sizes[0] / DF;   // 100000
    const int nE = in_sizes[1];        // 600000

    // workspace layout: [flag 256B][counts][agg][buckets]
    const size_t cnt_off   = 256;
    const size_t cnt_bytes = (((size_t)(M + 1) * 4) + 255) & ~(size_t)255;
    const size_t agg_off   = cnt_off + cnt_bytes;
    const size_t agg_bytes = (size_t)M * DF * sizeof(float);
    const size_t bkt_off   = agg_off + agg_bytes;
    const size_t bkt_bytes = (size_t)M * CAP * sizeof(int);

    int*   flag    = (int*)d_ws;
    int*   counts  = (int*)((char*)d_ws + cnt_off);
    float* agg     = (float*)((char*)d_ws + agg_off);
    int*   buckets = (int*)((char*)d_ws + bkt_off);

    // zero flag + counts + agg in one contiguous memset
    hipMemsetAsync(d_ws, 0, agg_off + agg_bytes, stream);

    detect_idx_kernel<<<1, 128, 0, stream>>>((const int*)src, nE, flag);

    if (ws_size >= bkt_off + bkt_bytes) {
        const int pblocks = (nE + 255) / 256;
        placement_kernel<<<pblocks, 256, 0, stream>>>(
            feat, src, dst, counts, buckets, agg, nE, flag);
        const int gblocks2 = (M * 32 + 255) / 256;
        gather_kernel<<<gblocks2, 256, 0, stream>>>(feat, counts, buckets, agg, M);
    } else {
        // insufficient workspace: fp32-atomic fallback
        const int sblocks = (int)(((long long)nE * 32 + 255) / 256);
        scatter_kernel<<<sblocks, 256, 0, stream>>>(feat, src, dst, agg, nE, flag);
    }

    const int gblocks = (M + BM - 1) / BM;
    gemm_kernel<<<gblocks, 256, 0, stream>>>(agg, feat, Wn, Wsf, bias, out, M);
}

// Round 3
// 226.503 us; speedup vs baseline: 5.3584x; 1.3423x over previous
//
#include <hip/hip_runtime.h>

#define DF 128     // feature dim
#define CAP 32     // bucket capacity per node (overflow -> atomic fallback)
#define GR 64      // GEMM rows per block

typedef __attribute__((ext_vector_type(8))) short short8;   // 8 bf16 (4 VGPRs)
typedef __attribute__((ext_vector_type(4))) float v4f;      // MFMA accumulator

__device__ __forceinline__ unsigned short f2bf(float x) {
    unsigned u = __float_as_uint(x);
    unsigned r = (u + 0x7FFFu + ((u >> 16) & 1u)) >> 16;    // RNE
    return (unsigned short)r;
}
__device__ __forceinline__ float bf2f(unsigned short h) {
    return __uint_as_float((unsigned)h << 16);
}

// ---------------------------------------------------------------------------
// Index dtype detection (int64 vs int32): odd int32 slots all-zero => int64.
// ---------------------------------------------------------------------------
__global__ __launch_bounds__(128) void detect_idx_kernel(
    const int* __restrict__ idx32, int n, int* __restrict__ flag32)
{
    int t = threadIdx.x;
    int found = 0;
    for (int i = t; i < 2048 && i < n; i += 128) {
        if (idx32[2 * i + 1] != 0) found = 1;
    }
    if (__any(found) && (t & 63) == 0) atomicOr(flag32, 1);
}

// ---------------------------------------------------------------------------
// Pre-transpose W into Bt[n][k] bf16, n in [0,256): [W_neigh | W_self] cols.
// Bt[n][k] = (n<128 ? Wn[k][n] : Ws[k][n-128])
// ---------------------------------------------------------------------------
__global__ __launch_bounds__(256) void prep_w_kernel(
    const float* __restrict__ Wn, const float* __restrict__ Ws,
    unsigned short* __restrict__ Bt)
{
    int idx = blockIdx.x * 256 + threadIdx.x;   // 256*128 = 32768 elements
    int n = idx >> 7, k = idx & 127;
    float v = (n < DF) ? Wn[(size_t)k * DF + n] : Ws[(size_t)k * DF + (n - DF)];
    Bt[idx] = f2bf(v);
}

// ---------------------------------------------------------------------------
// Fused MFMA GEMM over K=128: per 64-row block computes
//   Y[r][0:128]  = feat[r] @ Wn          -> Ybf (bf16)
//   out[r][0:128]= feat[r] @ Ws + bias   -> out (fp32)
// 4 waves: wave w owns output cols [w*64, w*64+64). Single barrier, K fits LDS.
// ---------------------------------------------------------------------------
__global__ __launch_bounds__(256) void gemm_kernel(
    const float* __restrict__ feat, const unsigned short* __restrict__ Bt,
    const float* __restrict__ bias, unsigned short* __restrict__ Ybf,
    float* __restrict__ out, int M)
{
    __shared__ unsigned short As[GR][136];      // bf16, stride 136 (16B-aligned rows)

    const int t = threadIdx.x;
    const int wave = t >> 6;
    const int lane = t & 63;
    const int nl   = lane & 15;                 // MFMA n / m sub-index
    const int quad = lane >> 4;                 // 0..3
    const int block_row = blockIdx.x * GR;

    // ---- stage A (fp32 -> bf16), 4 threads per row x 32 cols each ----
    {
        const int row = t >> 2;
        const int cb  = (t & 3) * 32;
        const int grow = block_row + row;
        const float* srcp = feat + (size_t)grow * DF + cb;
#pragma unroll
        for (int it = 0; it < 4; it++) {
            float4 v0, v1;
            if (grow < M) {
                v0 = reinterpret_cast<const float4*>(srcp)[it * 2];
                v1 = reinterpret_cast<const float4*>(srcp)[it * 2 + 1];
            } else {
                v0 = make_float4(0.f, 0.f, 0.f, 0.f);
                v1 = v0;
            }
            uint4 pk;
            pk.x = (unsigned)f2bf(v0.x) | ((unsigned)f2bf(v0.y) << 16);
            pk.y = (unsigned)f2bf(v0.z) | ((unsigned)f2bf(v0.w) << 16);
            pk.z = (unsigned)f2bf(v1.x) | ((unsigned)f2bf(v1.y) << 16);
            pk.w = (unsigned)f2bf(v1.z) | ((unsigned)f2bf(v1.w) << 16);
            *reinterpret_cast<uint4*>(&As[row][cb + it * 8]) = pk;
        }
    }

    // ---- preload B fragments (Bt is 64KB, L2-hot) ----
    const int n0 = wave * 64;
    short8 bfrag[4][4];
#pragma unroll
    for (int ct = 0; ct < 4; ct++)
#pragma unroll
        for (int kk = 0; kk < 4; kk++)
            bfrag[ct][kk] = *reinterpret_cast<const short8*>(
                Bt + (size_t)(n0 + ct * 16 + nl) * DF + kk * 32 + quad * 8);

    float bcol[4];
#pragma unroll
    for (int ct = 0; ct < 4; ct++) {
        int n = n0 + ct * 16 + nl;
        bcol[ct] = (n >= DF) ? bias[n - DF] : 0.f;
    }

    __syncthreads();

    // ---- compute: 4 row-tiles x 4 col-tiles x (K=128 as 4 mfma) ----
#pragma unroll
    for (int rt = 0; rt < 4; rt++) {
        short8 afrag[4];
#pragma unroll
        for (int kk = 0; kk < 4; kk++)
            afrag[kk] = *reinterpret_cast<const short8*>(
                &As[rt * 16 + nl][kk * 32 + quad * 8]);
#pragma unroll
        for (int ct = 0; ct < 4; ct++) {
            v4f acc = {0.f, 0.f, 0.f, 0.f};
#pragma unroll
            for (int kk = 0; kk < 4; kk++)
                acc = __builtin_amdgcn_mfma_f32_16x16x32_bf16(
                    afrag[kk], bfrag[ct][kk], acc, 0, 0, 0);
            const int n = n0 + ct * 16 + nl;      // output col (0..255)
#pragma unroll
            for (int r = 0; r < 4; r++) {
                const int grow = block_row + rt * 16 + quad * 4 + r;
                if (grow < M) {
                    if (n < DF)
                        Ybf[(size_t)grow * DF + n] = f2bf(acc[r]);
                    else
                        out[(size_t)grow * DF + (n - DF)] = acc[r] + bcol[ct];
                }
            }
        }
    }
}

// ---------------------------------------------------------------------------
// Placement: pos = count[dst]++; bucket[dst*CAP+pos] = src. Overflow (rare,
// Poisson(6) vs CAP=32) adds Y[src] directly into out via fp32 atomics.
// Must run AFTER gemm_kernel (needs Ybf/out valid for the overflow path).
// ---------------------------------------------------------------------------
__global__ __launch_bounds__(256) void placement_kernel(
    const void* __restrict__ src, const void* __restrict__ dst,
    int* __restrict__ counts, int* __restrict__ buckets,
    const unsigned short* __restrict__ Ybf, float* __restrict__ out,
    int nE, const int* __restrict__ flag32)
{
    int e = blockIdx.x * 256 + threadIdx.x;
    if (e >= nE) return;
    long long s, d;
    if (*flag32) {
        s = ((const int*)src)[e];
        d = ((const int*)dst)[e];
    } else {
        s = ((const long long*)src)[e];
        d = ((const long long*)dst)[e];
    }

    int pos = atomicAdd(&counts[d], 1);
    if (pos < CAP) {
        buckets[(size_t)d * CAP + pos] = (int)s;
    } else {
        const unsigned short* yr = Ybf + (size_t)s * DF;
        float* orow = out + (size_t)d * DF;
        for (int i = 0; i < DF; i++)
            unsafeAtomicAdd(orow + i, bf2f(yr[i]));
    }
}

// ---------------------------------------------------------------------------
// Gather: out[node] += sum over bucketed neighbors of Y[s] (bf16 rows, 256B).
// 32 lanes per node, 8B (ushort4) per lane; fp32 accumulate; single RMW of out.
// ---------------------------------------------------------------------------
__global__ __launch_bounds__(256) void gather_kernel(
    const unsigned short* __restrict__ Ybf,
    const int* __restrict__ counts, const int* __restrict__ buckets,
    float* __restrict__ out, int M)
{
    int gid = blockIdx.x * 256 + threadIdx.x;
    int node = gid >> 5;
    if (node >= M) return;
    int lane = gid & 31;

    int deg = counts[node];
    if (deg > CAP) deg = CAP;
    const int* b = buckets + (size_t)node * CAP;

    float4 acc = make_float4(0.f, 0.f, 0.f, 0.f);
    int e = 0;
    for (; e + 2 <= deg; e += 2) {
        int s0 = b[e], s1 = b[e + 1];
        ushort4 y0 = *reinterpret_cast<const ushort4*>(Ybf + (size_t)s0 * DF + lane * 4);
        ushort4 y1 = *reinterpret_cast<const ushort4*>(Ybf + (size_t)s1 * DF + lane * 4);
        acc.x += bf2f(y0.x) + bf2f(y1.x);
        acc.y += bf2f(y0.y) + bf2f(y1.y);
        acc.z += bf2f(y0.z) + bf2f(y1.z);
        acc.w += bf2f(y0.w) + bf2f(y1.w);
    }
    if (e < deg) {
        int s0 = b[e];
        ushort4 y0 = *reinterpret_cast<const ushort4*>(Ybf + (size_t)s0 * DF + lane * 4);
        acc.x += bf2f(y0.x);
        acc.y += bf2f(y0.y);
        acc.z += bf2f(y0.z);
        acc.w += bf2f(y0.w);
    }

    float* op = out + (size_t)node * DF + lane * 4;
    float4 o = *reinterpret_cast<const float4*>(op);
    o.x += acc.x; o.y += acc.y; o.z += acc.z; o.w += acc.w;
    *reinterpret_cast<float4*>(op) = o;
}

extern "C" void kernel_launch(void* const* d_in, const int* in_sizes, int n_in,
                              void* d_out, int out_size, void* d_ws, size_t ws_size,
                              hipStream_t stream) {
    const float* feat = (const float*)d_in[0];
    const void*  src  = d_in[1];
    const void*  dst  = d_in[2];
    const float* Wn   = (const float*)d_in[3];
    const float* bias = (const float*)d_in[4];
    const float* Wsf  = (const float*)d_in[5];
    float* out = (float*)d_out;

    const int M  = in_sizes[0] / DF;   // 100000
    const int nE = in_sizes[1];        // 600000

    // workspace: [flag 256B][counts][buckets][Bt 64KB][Ybf]
    const size_t cnt_off   = 256;
    const size_t cnt_bytes = (((size_t)(M + 1) * 4) + 255) & ~(size_t)255;
    const size_t bkt_off   = cnt_off + cnt_bytes;
    const size_t bkt_bytes = (size_t)M * CAP * sizeof(int);
    const size_t bt_off    = (bkt_off + bkt_bytes + 255) & ~(size_t)255;
    const size_t bt_bytes  = (size_t)256 * DF * sizeof(unsigned short);
    const size_t y_off     = bt_off + bt_bytes;

    int*            flag    = (int*)d_ws;
    int*            counts  = (int*)((char*)d_ws + cnt_off);
    int*            buckets = (int*)((char*)d_ws + bkt_off);
    unsigned short* Bt      = (unsigned short*)((char*)d_ws + bt_off);
    unsigned short* Ybf     = (unsigned short*)((char*)d_ws + y_off);

    // zero flag + counts only (agg buffer eliminated)
    hipMemsetAsync(d_ws, 0, cnt_off + cnt_bytes, stream);

    detect_idx_kernel<<<1, 128, 0, stream>>>((const int*)src, nE, flag);

    prep_w_kernel<<<128, 256, 0, stream>>>(Wn, Wsf, Bt);

    const int gemm_blocks = (M + GR - 1) / GR;
    gemm_kernel<<<gemm_blocks, 256, 0, stream>>>(feat, Bt, bias, Ybf, out, M);

    const int pblocks = (nE + 255) / 256;
    placement_kernel<<<pblocks, 256, 0, stream>>>(
        src, dst, counts, buckets, Ybf, out, nE, flag);

    const int gablocks = (int)(((long long)M * 32 + 255) / 256);
    gather_kernel<<<gablocks, 256, 0, stream>>>(Ybf, counts, buckets, out, M);
}

// Round 5
// 220.962 us; speedup vs baseline: 5.4927x; 1.0251x over previous
//
#include <hip/hip_runtime.h>

#define DF 128     // feature dim
#define CAP 16     // bucket capacity per node = one 64B cache line
#define GR 64      // GEMM rows per block

typedef __attribute__((ext_vector_type(8))) short short8;   // 8 bf16 (4 VGPRs)
typedef __attribute__((ext_vector_type(4))) float v4f;      // MFMA accumulator

__device__ __forceinline__ unsigned short f2bf(float x) {
    unsigned u = __float_as_uint(x);
    unsigned r = (u + 0x7FFFu + ((u >> 16) & 1u)) >> 16;    // RNE
    return (unsigned short)r;
}
__device__ __forceinline__ float bf2f(unsigned short h) {
    return __uint_as_float((unsigned)h << 16);
}
__device__ __forceinline__ unsigned pack2(float a, float b) {
    return (unsigned)f2bf(a) | ((unsigned)f2bf(b) << 16);
}

// ---------------------------------------------------------------------------
// Index dtype detection (int64 vs int32): odd int32 slots all-zero => int64.
// ---------------------------------------------------------------------------
__global__ __launch_bounds__(128) void detect_idx_kernel(
    const int* __restrict__ idx32, int n, int* __restrict__ flag32)
{
    int t = threadIdx.x;
    int found = 0;
    for (int i = t; i < 2048 && i < n; i += 128) {
        if (idx32[2 * i + 1] != 0) found = 1;
    }
    if (__any(found) && (t & 63) == 0) atomicOr(flag32, 1);
}

// ---------------------------------------------------------------------------
// Pre-transpose W into Bt[n][k] bf16, n in [0,256): [W_neigh | W_self] cols.
// ---------------------------------------------------------------------------
__global__ __launch_bounds__(256) void prep_w_kernel(
    const float* __restrict__ Wn, const float* __restrict__ Ws,
    unsigned short* __restrict__ Bt)
{
    int idx = blockIdx.x * 256 + threadIdx.x;   // 256*128 = 32768 elements
    int n = idx >> 7, k = idx & 127;
    float v = (n < DF) ? Wn[(size_t)k * DF + n] : Ws[(size_t)k * DF + (n - DF)];
    Bt[idx] = f2bf(v);
}

// ---------------------------------------------------------------------------
// Fused MFMA GEMM over K=128: per 64-row block computes
//   Y[r]   = feat[r] @ Wn          -> Ybf (bf16, LDS-staged coalesced store)
//   out[r] = feat[r] @ Ws + bias   -> out (fp32, direct 64B-segment stores)
// 4 waves; wave w owns output cols [w*64, w*64+64).
// ---------------------------------------------------------------------------
__global__ __launch_bounds__(256) void gemm_kernel(
    const float* __restrict__ feat, const unsigned short* __restrict__ Bt,
    const float* __restrict__ bias, unsigned short* __restrict__ Ybf,
    float* __restrict__ out, int M)
{
    __shared__ unsigned short As[GR][136];   // A tile bf16, 16B-aligned rows
    __shared__ unsigned short Ys[GR][136];   // Y staging bf16

    const int t = threadIdx.x;
    const int wave = t >> 6;
    const int lane = t & 63;
    const int nl   = lane & 15;
    const int quad = lane >> 4;
    const int block_row = blockIdx.x * GR;

    // ---- stage A: flat lane-contiguous float4 loads, pack bf16 -> LDS ----
    // 64x128 tile = 8192 floats; 256 threads x 8 iters x 4 floats = 8192.
    {
        const float* base = feat + (size_t)block_row * DF;
#pragma unroll
        for (int it = 0; it < 8; it++) {
            const int idx = t * 4 + it * 1024;      // float index in tile
            const int row = idx >> 7, col = idx & 127;
            float4 v;
            if (block_row + row < M)
                v = *reinterpret_cast<const float4*>(base + idx);
            else
                v = make_float4(0.f, 0.f, 0.f, 0.f);
            uint2 pk;
            pk.x = pack2(v.x, v.y);
            pk.y = pack2(v.z, v.w);
            *reinterpret_cast<uint2*>(&As[row][col]) = pk;
        }
    }

    // ---- preload B fragments (Bt is 64KB, L2-hot) ----
    const int n0 = wave * 64;
    short8 bfrag[4][4];
#pragma unroll
    for (int ct = 0; ct < 4; ct++)
#pragma unroll
        for (int kk = 0; kk < 4; kk++)
            bfrag[ct][kk] = *reinterpret_cast<const short8*>(
                Bt + (size_t)(n0 + ct * 16 + nl) * DF + kk * 32 + quad * 8);

    float bcol[4];
#pragma unroll
    for (int ct = 0; ct < 4; ct++) {
        int n = n0 + ct * 16 + nl;
        bcol[ct] = (n >= DF) ? bias[n - DF] : 0.f;
    }

    __syncthreads();

    // ---- compute: 4 row-tiles x 4 col-tiles x (K=128 as 4 mfma) ----
#pragma unroll
    for (int rt = 0; rt < 4; rt++) {
        short8 afrag[4];
#pragma unroll
        for (int kk = 0; kk < 4; kk++)
            afrag[kk] = *reinterpret_cast<const short8*>(
                &As[rt * 16 + nl][kk * 32 + quad * 8]);
#pragma unroll
        for (int ct = 0; ct < 4; ct++) {
            v4f acc = {0.f, 0.f, 0.f, 0.f};
#pragma unroll
            for (int kk = 0; kk < 4; kk++)
                acc = __builtin_amdgcn_mfma_f32_16x16x32_bf16(
                    afrag[kk], bfrag[ct][kk], acc, 0, 0, 0);
            const int n = n0 + ct * 16 + nl;          // output col (0..255)
            const int lrow = rt * 16 + quad * 4;      // local row base
            if (n < DF) {
#pragma unroll
                for (int r = 0; r < 4; r++)
                    Ys[lrow + r][n] = f2bf(acc[r]);   // LDS stage (always safe)
            } else {
#pragma unroll
                for (int r = 0; r < 4; r++) {
                    const int grow = block_row + lrow + r;
                    if (grow < M)
                        out[(size_t)grow * DF + (n - DF)] = acc[r] + bcol[ct];
                }
            }
        }
    }

    __syncthreads();

    // ---- coalesced Y writeback: 16B/lane uint4 stores ----
    {
        const int row = t >> 2;
        const int cb  = (t & 3) * 32;                 // 32 ushorts = 64B per thread
        const int grow = block_row + row;
        if (grow < M) {
            const uint4* srcp = reinterpret_cast<const uint4*>(&Ys[row][cb]);
            uint4* dstp = reinterpret_cast<uint4*>(Ybf + (size_t)grow * DF + cb);
            dstp[0] = srcp[0];
            dstp[1] = srcp[1];
            dstp[2] = srcp[2];
            dstp[3] = srcp[3];
        }
    }
}

// ---------------------------------------------------------------------------
// Placement: pos = count[dst]++; bucket[dst*CAP+pos] = src. Overflow (rare,
// Poisson(6) vs CAP=16, ~16 nodes expected) adds Y[src] into out via atomics.
// Runs AFTER gemm_kernel (overflow path needs Ybf/out valid).
// ---------------------------------------------------------------------------
__global__ __launch_bounds__(256) void placement_kernel(
    const void* __restrict__ src, const void* __restrict__ dst,
    int* __restrict__ counts, int* __restrict__ buckets,
    const unsigned short* __restrict__ Ybf, float* __restrict__ out,
    int nE, const int* __restrict__ flag32)
{
    int e = blockIdx.x * 256 + threadIdx.x;
    if (e >= nE) return;
    long long s, d;
    if (*flag32) {
        s = ((const int*)src)[e];
        d = ((const int*)dst)[e];
    } else {
        s = ((const long long*)src)[e];
        d = ((const long long*)dst)[e];
    }

    int pos = atomicAdd(&counts[d], 1);
    if (pos < CAP) {
        buckets[(size_t)d * CAP + pos] = (int)s;
    } else {
        const unsigned short* yr = Ybf + (size_t)s * DF;
        float* orow = out + (size_t)d * DF;
        for (int i = 0; i < DF; i++)
            unsafeAtomicAdd(orow + i, bf2f(yr[i]));
    }
}

// ---------------------------------------------------------------------------
// Gather: out[node] += sum over bucketed neighbors of Y[s] (bf16 rows, 256B).
// 32 lanes per node, ushort4/lane; unroll 4 for MLP; single RMW of out.
// ---------------------------------------------------------------------------
__global__ __launch_bounds__(256) void gather_kernel(
    const unsigned short* __restrict__ Ybf,
    const int* __restrict__ counts, const int* __restrict__ buckets,
    float* __restrict__ out, int M)
{
    int gid = blockIdx.x * 256 + threadIdx.x;
    int node = gid >> 5;
    if (node >= M) return;
    int lane = gid & 31;

    int deg = counts[node];
    if (deg > CAP) deg = CAP;
    const int* b = buckets + (size_t)node * CAP;

    float4 acc = make_float4(0.f, 0.f, 0.f, 0.f);
    int e = 0;
    for (; e + 4 <= deg; e += 4) {
        int4 ss = *reinterpret_cast<const int4*>(b + e);   // 16B-aligned
        ushort4 y0 = *reinterpret_cast<const ushort4*>(Ybf + (size_t)ss.x * DF + lane * 4);
        ushort4 y1 = *reinterpret_cast<const ushort4*>(Ybf + (size_t)ss.y * DF + lane * 4);
        ushort4 y2 = *reinterpret_cast<const ushort4*>(Ybf + (size_t)ss.z * DF + lane * 4);
        ushort4 y3 = *reinterpret_cast<const ushort4*>(Ybf + (size_t)ss.w * DF + lane * 4);
        acc.x += (bf2f(y0.x) + bf2f(y1.x)) + (bf2f(y2.x) + bf2f(y3.x));
        acc.y += (bf2f(y0.y) + bf2f(y1.y)) + (bf2f(y2.y) + bf2f(y3.y));
        acc.z += (bf2f(y0.z) + bf2f(y1.z)) + (bf2f(y2.z) + bf2f(y3.z));
        acc.w += (bf2f(y0.w) + bf2f(y1.w)) + (bf2f(y2.w) + bf2f(y3.w));
    }
    for (; e < deg; e++) {
        int s0 = b[e];
        ushort4 y0 = *reinterpret_cast<const ushort4*>(Ybf + (size_t)s0 * DF + lane * 4);
        acc.x += bf2f(y0.x);
        acc.y += bf2f(y0.y);
        acc.z += bf2f(y0.z);
        acc.w += bf2f(y0.w);
    }

    float* op = out + (size_t)node * DF + lane * 4;
    float4 o = *reinterpret_cast<const float4*>(op);
    o.x += acc.x; o.y += acc.y; o.z += acc.z; o.w += acc.w;
    *reinterpret_cast<float4*>(op) = o;
}

extern "C" void kernel_launch(void* const* d_in, const int* in_sizes, int n_in,
                              void* d_out, int out_size, void* d_ws, size_t ws_size,
                              hipStream_t stream) {
    const float* feat = (const float*)d_in[0];
    const void*  src  = d_in[1];
    const void*  dst  = d_in[2];
    const float* Wn   = (const float*)d_in[3];
    const float* bias = (const float*)d_in[4];
    const float* Wsf  = (const float*)d_in[5];
    float* out = (float*)d_out;

    const int M  = in_sizes[0] / DF;   // 100000
    const int nE = in_sizes[1];        // 600000

    // workspace: [flag 256B][counts][buckets][Bt 64KB][Ybf]
    const size_t cnt_off   = 256;
    const size_t cnt_bytes = (((size_t)(M + 1) * 4) + 255) & ~(size_t)255;
    const size_t bkt_off   = cnt_off + cnt_bytes;
    const size_t bkt_bytes = (size_t)M * CAP * sizeof(int);
    const size_t bt_off    = (bkt_off + bkt_bytes + 255) & ~(size_t)255;
    const size_t bt_bytes  = (size_t)256 * DF * sizeof(unsigned short);
    const size_t y_off     = bt_off + bt_bytes;

    int*            flag    = (int*)d_ws;
    int*            counts  = (int*)((char*)d_ws + cnt_off);
    int*            buckets = (int*)((char*)d_ws + bkt_off);
    unsigned short* Bt      = (unsigned short*)((char*)d_ws + bt_off);
    unsigned short* Ybf     = (unsigned short*)((char*)d_ws + y_off);

    hipMemsetAsync(d_ws, 0, cnt_off + cnt_bytes, stream);

    detect_idx_kernel<<<1, 128, 0, stream>>>((const int*)src, nE, flag);

    prep_w_kernel<<<128, 256, 0, stream>>>(Wn, Wsf, Bt);

    const int gemm_blocks = (M + GR - 1) / GR;
    gemm_kernel<<<gemm_blocks, 256, 0, stream>>>(feat, Bt, bias, Ybf, out, M);

    const int pblocks = (nE + 255) / 256;
    placement_kernel<<<pblocks, 256, 0, stream>>>(
        src, dst, counts, buckets, Ybf, out, nE, flag);

    const int gablocks = (int)(((long long)M * 32 + 255) / 256);
    gather_kernel<<<gablocks, 256, 0, stream>>>(Ybf, counts, buckets, out, M);
}

// Round 6
// 209.362 us; speedup vs baseline: 5.7971x; 1.0554x over previous
//
#include <hip/hip_runtime.h>

#define DF 128     // feature dim
#define CAP 16     // bucket capacity per node = one 64B cache line
#define GR 64      // GEMM rows per block

typedef __attribute__((ext_vector_type(8))) short short8;   // 8 bf16 (4 VGPRs)
typedef __attribute__((ext_vector_type(4))) float v4f;      // MFMA accumulator

__device__ __forceinline__ unsigned short f2bf(float x) {
    unsigned u = __float_as_uint(x);
    unsigned r = (u + 0x7FFFu + ((u >> 16) & 1u)) >> 16;    // RNE
    return (unsigned short)r;
}
__device__ __forceinline__ float bf2f(unsigned short h) {
    return __uint_as_float((unsigned)h << 16);
}
__device__ __forceinline__ unsigned pack2(float a, float b) {
    return (unsigned)f2bf(a) | ((unsigned)f2bf(b) << 16);
}

// ---------------------------------------------------------------------------
// prep: block 0 = index-dtype detect + header init; blocks 1..128 = W
// transpose to Bt[n][k] bf16; blocks 129.. = zero counts.
// hdr[0] = 1 if indices are int32 (any odd int32 slot nonzero), else 0 (int64)
// hdr[1] = overflow counter (zeroed)
// ---------------------------------------------------------------------------
__global__ __launch_bounds__(256) void prep_kernel(
    const int* __restrict__ idx32, int nE, int* __restrict__ hdr,
    const float* __restrict__ Wn, const float* __restrict__ Ws,
    unsigned short* __restrict__ Bt, int* __restrict__ counts, int cnt_ints)
{
    const int b = blockIdx.x;
    const int t = threadIdx.x;
    if (b == 0) {
        __shared__ int sh;
        if (t == 0) sh = 0;
        __syncthreads();
        int found = 0;
        for (int i = t; i < 2048 && i < nE; i += 256)
            if (idx32[2 * i + 1] != 0) found = 1;
        if (found) sh = 1;                 // benign race, any writer sets 1
        __syncthreads();
        if (t == 0) { hdr[0] = sh; hdr[1] = 0; }
    } else if (b <= 128) {
        int idx = (b - 1) * 256 + t;       // 0..32767 over [n][k]
        int n = idx >> 7, k = idx & 127;
        float v = (n < DF) ? Wn[(size_t)k * DF + n] : Ws[(size_t)k * DF + (n - DF)];
        Bt[idx] = f2bf(v);
    } else {
        int off = ((b - 129) * 256 + t) * 4;   // int index, int4 stores
        if (off < cnt_ints)
            *reinterpret_cast<int4*>(counts + off) = make_int4(0, 0, 0, 0);
    }
}

// ---------------------------------------------------------------------------
// gemmplace: per 64-row block computes
//   Y[r]   = feat[r] @ Wn          -> Ybf (bf16, LDS-staged coalesced store)
//   out[r] = feat[r] @ Ws + bias   -> out (fp32)
// then places ~EPB edges into per-dst buckets (overflow -> ovf list).
// ---------------------------------------------------------------------------
__global__ __launch_bounds__(256) void gemmplace_kernel(
    const float* __restrict__ feat, const unsigned short* __restrict__ Bt,
    const float* __restrict__ bias, unsigned short* __restrict__ Ybf,
    float* __restrict__ out, int M,
    const void* __restrict__ src, const void* __restrict__ dst, int nE, int EPB,
    int* __restrict__ hdr, int* __restrict__ counts, int* __restrict__ buckets,
    int2* __restrict__ ovf)
{
    __shared__ unsigned short As[GR][136];   // A tile bf16
    __shared__ unsigned short Ys[GR][136];   // Y staging bf16

    const int t = threadIdx.x;
    const int wave = t >> 6;
    const int lane = t & 63;
    const int nl   = lane & 15;
    const int quad = lane >> 4;
    const int block_row = blockIdx.x * GR;

    // ---- stage A: flat lane-contiguous float4 loads, pack bf16 -> LDS ----
    {
        const float* base = feat + (size_t)block_row * DF;
#pragma unroll
        for (int it = 0; it < 8; it++) {
            const int idx = t * 4 + it * 1024;
            const int row = idx >> 7, col = idx & 127;
            float4 v;
            if (block_row + row < M)
                v = *reinterpret_cast<const float4*>(base + idx);
            else
                v = make_float4(0.f, 0.f, 0.f, 0.f);
            uint2 pk;
            pk.x = pack2(v.x, v.y);
            pk.y = pack2(v.z, v.w);
            *reinterpret_cast<uint2*>(&As[row][col]) = pk;
        }
    }

    // ---- preload B fragments (Bt is 64KB, L2-hot) ----
    const int n0 = wave * 64;
    short8 bfrag[4][4];
#pragma unroll
    for (int ct = 0; ct < 4; ct++)
#pragma unroll
        for (int kk = 0; kk < 4; kk++)
            bfrag[ct][kk] = *reinterpret_cast<const short8*>(
                Bt + (size_t)(n0 + ct * 16 + nl) * DF + kk * 32 + quad * 8);

    float bcol[4];
#pragma unroll
    for (int ct = 0; ct < 4; ct++) {
        int n = n0 + ct * 16 + nl;
        bcol[ct] = (n >= DF) ? bias[n - DF] : 0.f;
    }

    __syncthreads();

    // ---- compute: 4 row-tiles x 4 col-tiles x (K=128 as 4 mfma) ----
#pragma unroll
    for (int rt = 0; rt < 4; rt++) {
        short8 afrag[4];
#pragma unroll
        for (int kk = 0; kk < 4; kk++)
            afrag[kk] = *reinterpret_cast<const short8*>(
                &As[rt * 16 + nl][kk * 32 + quad * 8]);
#pragma unroll
        for (int ct = 0; ct < 4; ct++) {
            v4f acc = {0.f, 0.f, 0.f, 0.f};
#pragma unroll
            for (int kk = 0; kk < 4; kk++)
                acc = __builtin_amdgcn_mfma_f32_16x16x32_bf16(
                    afrag[kk], bfrag[ct][kk], acc, 0, 0, 0);
            const int n = n0 + ct * 16 + nl;
            const int lrow = rt * 16 + quad * 4;
            if (n < DF) {
#pragma unroll
                for (int r = 0; r < 4; r++)
                    Ys[lrow + r][n] = f2bf(acc[r]);
            } else {
#pragma unroll
                for (int r = 0; r < 4; r++) {
                    const int grow = block_row + lrow + r;
                    if (grow < M)
                        out[(size_t)grow * DF + (n - DF)] = acc[r] + bcol[ct];
                }
            }
        }
    }

    __syncthreads();

    // ---- coalesced Y writeback: 16B/lane uint4 stores ----
    {
        const int row = t >> 2;
        const int cb  = (t & 3) * 32;
        const int grow = block_row + row;
        if (grow < M) {
            const uint4* srcp = reinterpret_cast<const uint4*>(&Ys[row][cb]);
            uint4* dstp = reinterpret_cast<uint4*>(Ybf + (size_t)grow * DF + cb);
            dstp[0] = srcp[0];
            dstp[1] = srcp[1];
            dstp[2] = srcp[2];
            dstp[3] = srcp[3];
        }
    }

    // ---- placement: edges [blk*EPB, min(nE, (blk+1)*EPB)) ----
    {
        const int is32 = hdr[0];
        const int e_end = min(nE, (int)(blockIdx.x + 1) * EPB);
        for (int e = blockIdx.x * EPB + t; e < e_end; e += 256) {
            long long s, d;
            if (is32) {
                s = ((const int*)src)[e];
                d = ((const int*)dst)[e];
            } else {
                s = ((const long long*)src)[e];
                d = ((const long long*)dst)[e];
            }
            int pos = atomicAdd(&counts[d], 1);
            if (pos < CAP) {
                buckets[(size_t)d * CAP + pos] = (int)s;
            } else {
                int oi = atomicAdd(&hdr[1], 1);
                ovf[oi] = make_int2((int)s, (int)d);
            }
        }
    }
}

// ---------------------------------------------------------------------------
// gather: out[node] += sum over bucketed neighbors of Y[s] (bf16 rows).
// 32 lanes per node, ushort4/lane. Nodes with counts>CAP use atomics (their
// remaining edges arrive via the overflow list, processed grid-stride below).
// ---------------------------------------------------------------------------
__global__ __launch_bounds__(256) void gather_kernel(
    const unsigned short* __restrict__ Ybf,
    const int* __restrict__ counts, const int* __restrict__ buckets,
    const int* __restrict__ hdr, const int2* __restrict__ ovf,
    float* __restrict__ out, int M, int ngroups)
{
    int gid = blockIdx.x * 256 + threadIdx.x;
    int node = gid >> 5;
    int lane = gid & 31;

    if (node < M) {
        int deg_raw = counts[node];
        int deg = min(deg_raw, CAP);
        const int* b = buckets + (size_t)node * CAP;

        float4 acc = make_float4(0.f, 0.f, 0.f, 0.f);
        int e = 0;
        for (; e + 4 <= deg; e += 4) {
            int4 ss = *reinterpret_cast<const int4*>(b + e);
            ushort4 y0 = *reinterpret_cast<const ushort4*>(Ybf + (size_t)ss.x * DF + lane * 4);
            ushort4 y1 = *reinterpret_cast<const ushort4*>(Ybf + (size_t)ss.y * DF + lane * 4);
            ushort4 y2 = *reinterpret_cast<const ushort4*>(Ybf + (size_t)ss.z * DF + lane * 4);
            ushort4 y3 = *reinterpret_cast<const ushort4*>(Ybf + (size_t)ss.w * DF + lane * 4);
            acc.x += (bf2f(y0.x) + bf2f(y1.x)) + (bf2f(y2.x) + bf2f(y3.x));
            acc.y += (bf2f(y0.y) + bf2f(y1.y)) + (bf2f(y2.y) + bf2f(y3.y));
            acc.z += (bf2f(y0.z) + bf2f(y1.z)) + (bf2f(y2.z) + bf2f(y3.z));
            acc.w += (bf2f(y0.w) + bf2f(y1.w)) + (bf2f(y2.w) + bf2f(y3.w));
        }
        for (; e < deg; e++) {
            int s0 = b[e];
            ushort4 y0 = *reinterpret_cast<const ushort4*>(Ybf + (size_t)s0 * DF + lane * 4);
            acc.x += bf2f(y0.x);
            acc.y += bf2f(y0.y);
            acc.z += bf2f(y0.z);
            acc.w += bf2f(y0.w);
        }

        float* op = out + (size_t)node * DF + lane * 4;
        if (deg_raw <= CAP) {
            float4 o = *reinterpret_cast<const float4*>(op);
            o.x += acc.x; o.y += acc.y; o.z += acc.z; o.w += acc.w;
            *reinterpret_cast<float4*>(op) = o;
        } else {
            // overflow node: compose with overflow-list atomics below
            unsafeAtomicAdd(op + 0, acc.x);
            unsafeAtomicAdd(op + 1, acc.y);
            unsafeAtomicAdd(op + 2, acc.z);
            unsafeAtomicAdd(op + 3, acc.w);
        }
    }

    // ---- overflow edges, grid-stride over 32-lane groups ----
    int n_ovf = hdr[1];
    for (int i = gid >> 5; i < n_ovf; i += ngroups) {
        int2 sd = ovf[i];
        ushort4 y = *reinterpret_cast<const ushort4*>(
            Ybf + (size_t)sd.x * DF + lane * 4);
        float* op = out + (size_t)sd.y * DF + lane * 4;
        unsafeAtomicAdd(op + 0, bf2f(y.x));
        unsafeAtomicAdd(op + 1, bf2f(y.y));
        unsafeAtomicAdd(op + 2, bf2f(y.z));
        unsafeAtomicAdd(op + 3, bf2f(y.w));
    }
}

extern "C" void kernel_launch(void* const* d_in, const int* in_sizes, int n_in,
                              void* d_out, int out_size, void* d_ws, size_t ws_size,
                              hipStream_t stream) {
    const float* feat = (const float*)d_in[0];
    const void*  src  = d_in[1];
    const void*  dst  = d_in[2];
    const float* Wn   = (const float*)d_in[3];
    const float* bias = (const float*)d_in[4];
    const float* Wsf  = (const float*)d_in[5];
    float* out = (float*)d_out;

    const int M  = in_sizes[0] / DF;   // 100000
    const int nE = in_sizes[1];        // 600000

    // workspace: [hdr 256B][counts][buckets][Bt 64KB][Ybf][ovf]
    const size_t cnt_off   = 256;
    const size_t cnt_bytes = (((size_t)(M + 1) * 4) + 255) & ~(size_t)255;
    const size_t bkt_off   = cnt_off + cnt_bytes;
    const size_t bkt_bytes = (size_t)M * CAP * sizeof(int);
    const size_t bt_off    = (bkt_off + bkt_bytes + 255) & ~(size_t)255;
    const size_t bt_bytes  = (size_t)256 * DF * sizeof(unsigned short);
    const size_t y_off     = bt_off + bt_bytes;
    const size_t y_bytes   = (size_t)M * DF * sizeof(unsigned short);
    const size_t ovf_off   = (y_off + y_bytes + 255) & ~(size_t)255;

    int*            hdr     = (int*)d_ws;
    int*            counts  = (int*)((char*)d_ws + cnt_off);
    int*            buckets = (int*)((char*)d_ws + bkt_off);
    unsigned short* Bt      = (unsigned short*)((char*)d_ws + bt_off);
    unsigned short* Ybf     = (unsigned short*)((char*)d_ws + y_off);
    int2*           ovf     = (int2*)((char*)d_ws + ovf_off);

    const int cnt_ints = (int)(cnt_bytes / 4);
    const int nzb = (cnt_ints + 1023) / 1024;          // zeroing blocks
    prep_kernel<<<1 + 128 + nzb, 256, 0, stream>>>(
        (const int*)src, nE, hdr, Wn, Wsf, Bt, counts, cnt_ints);

    const int gemm_blocks = (M + GR - 1) / GR;
    const int EPB = (nE + gemm_blocks - 1) / gemm_blocks;
    gemmplace_kernel<<<gemm_blocks, 256, 0, stream>>>(
        feat, Bt, bias, Ybf, out, M, src, dst, nE, EPB,
        hdr, counts, buckets, ovf);

    const int gablocks = (int)(((long long)M * 32 + 255) / 256);
    const int ngroups = gablocks * 8;
    gather_kernel<<<gablocks, 256, 0, stream>>>(
        Ybf, counts, buckets, hdr, ovf, out, M, ngroups);
}

// Round 7
// 192.606 us; speedup vs baseline: 6.3014x; 1.0870x over previous
//
#include <hip/hip_runtime.h>

#define DF 128     // feature dim
#define CAP 16     // bucket capacity per node = one 64B cache line
#define GR 64      // GEMM rows per block
#define PBLK 256   // placement blocks (block-specialized, run concurrently w/ GEMM)

typedef __attribute__((ext_vector_type(8))) short short8;   // 8 bf16 (4 VGPRs)
typedef __attribute__((ext_vector_type(4))) float v4f;      // MFMA accumulator

__device__ __forceinline__ unsigned short f2bf(float x) {
    unsigned u = __float_as_uint(x);
    unsigned r = (u + 0x7FFFu + ((u >> 16) & 1u)) >> 16;    // RNE
    return (unsigned short)r;
}
__device__ __forceinline__ float bf2f(unsigned short h) {
    return __uint_as_float((unsigned)h << 16);
}
__device__ __forceinline__ unsigned pack2(float a, float b) {
    return (unsigned)f2bf(a) | ((unsigned)f2bf(b) << 16);
}

// ---------------------------------------------------------------------------
// prep: block 0 = index-dtype detect + header init; blocks 1..128 = W
// transpose to Bt[n][k] bf16; blocks 129.. = zero counts.
// hdr[0] = 1 if indices are int32, else 0 (int64). hdr[1] = overflow counter.
// ---------------------------------------------------------------------------
__global__ __launch_bounds__(256) void prep_kernel(
    const int* __restrict__ idx32, int nE, int* __restrict__ hdr,
    const float* __restrict__ Wn, const float* __restrict__ Ws,
    unsigned short* __restrict__ Bt, int* __restrict__ counts, int cnt_ints)
{
    const int b = blockIdx.x;
    const int t = threadIdx.x;
    if (b == 0) {
        __shared__ int sh;
        if (t == 0) sh = 0;
        __syncthreads();
        int found = 0;
        for (int i = t; i < 2048 && i < nE; i += 256)
            if (idx32[2 * i + 1] != 0) found = 1;
        if (found) sh = 1;                 // benign race, any writer sets 1
        __syncthreads();
        if (t == 0) { hdr[0] = sh; hdr[1] = 0; }
    } else if (b <= 128) {
        int idx = (b - 1) * 256 + t;       // 0..32767 over [n][k]
        int n = idx >> 7, k = idx & 127;
        float v = (n < DF) ? Wn[(size_t)k * DF + n] : Ws[(size_t)k * DF + (n - DF)];
        Bt[idx] = f2bf(v);
    } else {
        int off = ((b - 129) * 256 + t) * 4;   // int index, int4 stores
        if (off < cnt_ints)
            *reinterpret_cast<int4*>(counts + off) = make_int4(0, 0, 0, 0);
    }
}

// ---------------------------------------------------------------------------
// fused: blocks [0,PBLK) = edge placement (grid-stride); blocks [PBLK, ...)
// = GEMM tiles. Disjoint data -> true concurrent execution across CUs.
//   GEMM tile: Y[r] = feat[r]@Wn -> Ybf (bf16); out[r] = feat[r]@Ws + bias.
//   Placement: pos = counts[dst]++; bucket or overflow list.
// ---------------------------------------------------------------------------
__global__ __launch_bounds__(256) void fused_kernel(
    const float* __restrict__ feat, const unsigned short* __restrict__ Bt,
    const float* __restrict__ bias, unsigned short* __restrict__ Ybf,
    float* __restrict__ out, int M,
    const void* __restrict__ src, const void* __restrict__ dst, int nE,
    int* __restrict__ hdr, int* __restrict__ counts, int* __restrict__ buckets,
    int2* __restrict__ ovf)
{
    const int t = threadIdx.x;

    if (blockIdx.x < PBLK) {
        // ---------------- placement blocks ----------------
        const int is32 = hdr[0];
        const int stride = PBLK * 256;
        if (is32) {
            const int* sp = (const int*)src;
            const int* dp = (const int*)dst;
            for (int e = blockIdx.x * 256 + t; e < nE; e += stride) {
                int s = sp[e], d = dp[e];
                int pos = atomicAdd(&counts[d], 1);
                if (pos < CAP) {
                    buckets[(size_t)d * CAP + pos] = s;
                } else {
                    int oi = atomicAdd(&hdr[1], 1);
                    ovf[oi] = make_int2(s, d);
                }
            }
        } else {
            const long long* sp = (const long long*)src;
            const long long* dp = (const long long*)dst;
            for (int e = blockIdx.x * 256 + t; e < nE; e += stride) {
                int s = (int)sp[e], d = (int)dp[e];
                int pos = atomicAdd(&counts[d], 1);
                if (pos < CAP) {
                    buckets[(size_t)d * CAP + pos] = s;
                } else {
                    int oi = atomicAdd(&hdr[1], 1);
                    ovf[oi] = make_int2(s, d);
                }
            }
        }
        return;
    }

    // ---------------- GEMM blocks ----------------
    __shared__ unsigned short As[GR][136];   // A tile bf16
    __shared__ unsigned short Ys[GR][136];   // Y staging bf16

    const int wave = t >> 6;
    const int lane = t & 63;
    const int nl   = lane & 15;
    const int quad = lane >> 4;
    const int block_row = (blockIdx.x - PBLK) * GR;

    // ---- stage A: flat lane-contiguous float4 loads, pack bf16 -> LDS ----
    {
        const float* base = feat + (size_t)block_row * DF;
#pragma unroll
        for (int it = 0; it < 8; it++) {
            const int idx = t * 4 + it * 1024;
            const int row = idx >> 7, col = idx & 127;
            float4 v;
            if (block_row + row < M)
                v = *reinterpret_cast<const float4*>(base + idx);
            else
                v = make_float4(0.f, 0.f, 0.f, 0.f);
            uint2 pk;
            pk.x = pack2(v.x, v.y);
            pk.y = pack2(v.z, v.w);
            *reinterpret_cast<uint2*>(&As[row][col]) = pk;
        }
    }

    // ---- preload B fragments (Bt is 64KB, L2-hot) ----
    const int n0 = wave * 64;
    short8 bfrag[4][4];
#pragma unroll
    for (int ct = 0; ct < 4; ct++)
#pragma unroll
        for (int kk = 0; kk < 4; kk++)
            bfrag[ct][kk] = *reinterpret_cast<const short8*>(
                Bt + (size_t)(n0 + ct * 16 + nl) * DF + kk * 32 + quad * 8);

    float bcol[4];
#pragma unroll
    for (int ct = 0; ct < 4; ct++) {
        int n = n0 + ct * 16 + nl;
        bcol[ct] = (n >= DF) ? bias[n - DF] : 0.f;
    }

    __syncthreads();

    // ---- compute: 4 row-tiles x 4 col-tiles x (K=128 as 4 mfma) ----
#pragma unroll
    for (int rt = 0; rt < 4; rt++) {
        short8 afrag[4];
#pragma unroll
        for (int kk = 0; kk < 4; kk++)
            afrag[kk] = *reinterpret_cast<const short8*>(
                &As[rt * 16 + nl][kk * 32 + quad * 8]);
#pragma unroll
        for (int ct = 0; ct < 4; ct++) {
            v4f acc = {0.f, 0.f, 0.f, 0.f};
#pragma unroll
            for (int kk = 0; kk < 4; kk++)
                acc = __builtin_amdgcn_mfma_f32_16x16x32_bf16(
                    afrag[kk], bfrag[ct][kk], acc, 0, 0, 0);
            const int n = n0 + ct * 16 + nl;
            const int lrow = rt * 16 + quad * 4;
            if (n < DF) {
#pragma unroll
                for (int r = 0; r < 4; r++)
                    Ys[lrow + r][n] = f2bf(acc[r]);
            } else {
#pragma unroll
                for (int r = 0; r < 4; r++) {
                    const int grow = block_row + lrow + r;
                    if (grow < M)
                        out[(size_t)grow * DF + (n - DF)] = acc[r] + bcol[ct];
                }
            }
        }
    }

    __syncthreads();

    // ---- coalesced Y writeback: 16B/lane uint4 stores ----
    {
        const int row = t >> 2;
        const int cb  = (t & 3) * 32;
        const int grow = block_row + row;
        if (grow < M) {
            const uint4* srcp = reinterpret_cast<const uint4*>(&Ys[row][cb]);
            uint4* dstp = reinterpret_cast<uint4*>(Ybf + (size_t)grow * DF + cb);
            dstp[0] = srcp[0];
            dstp[1] = srcp[1];
            dstp[2] = srcp[2];
            dstp[3] = srcp[3];
        }
    }
}

// ---------------------------------------------------------------------------
// gather: out[node] += sum over bucketed neighbors of Y[s] (bf16 rows).
// 32 lanes per node, ushort4/lane. Overflow-list edges handled grid-stride
// with atomics; overflow nodes use atomics for their bucketed part too.
// ---------------------------------------------------------------------------
__global__ __launch_bounds__(256) void gather_kernel(
    const unsigned short* __restrict__ Ybf,
    const int* __restrict__ counts, const int* __restrict__ buckets,
    const int* __restrict__ hdr, const int2* __restrict__ ovf,
    float* __restrict__ out, int M, int ngroups)
{
    int gid = blockIdx.x * 256 + threadIdx.x;
    int node = gid >> 5;
    int lane = gid & 31;

    if (node < M) {
        int deg_raw = counts[node];
        int deg = min(deg_raw, CAP);
        const int* b = buckets + (size_t)node * CAP;

        float4 acc = make_float4(0.f, 0.f, 0.f, 0.f);
        int e = 0;
        for (; e + 4 <= deg; e += 4) {
            int4 ss = *reinterpret_cast<const int4*>(b + e);
            ushort4 y0 = *reinterpret_cast<const ushort4*>(Ybf + (size_t)ss.x * DF + lane * 4);
            ushort4 y1 = *reinterpret_cast<const ushort4*>(Ybf + (size_t)ss.y * DF + lane * 4);
            ushort4 y2 = *reinterpret_cast<const ushort4*>(Ybf + (size_t)ss.z * DF + lane * 4);
            ushort4 y3 = *reinterpret_cast<const ushort4*>(Ybf + (size_t)ss.w * DF + lane * 4);
            acc.x += (bf2f(y0.x) + bf2f(y1.x)) + (bf2f(y2.x) + bf2f(y3.x));
            acc.y += (bf2f(y0.y) + bf2f(y1.y)) + (bf2f(y2.y) + bf2f(y3.y));
            acc.z += (bf2f(y0.z) + bf2f(y1.z)) + (bf2f(y2.z) + bf2f(y3.z));
            acc.w += (bf2f(y0.w) + bf2f(y1.w)) + (bf2f(y2.w) + bf2f(y3.w));
        }
        for (; e < deg; e++) {
            int s0 = b[e];
            ushort4 y0 = *reinterpret_cast<const ushort4*>(Ybf + (size_t)s0 * DF + lane * 4);
            acc.x += bf2f(y0.x);
            acc.y += bf2f(y0.y);
            acc.z += bf2f(y0.z);
            acc.w += bf2f(y0.w);
        }

        float* op = out + (size_t)node * DF + lane * 4;
        if (deg_raw <= CAP) {
            float4 o = *reinterpret_cast<const float4*>(op);
            o.x += acc.x; o.y += acc.y; o.z += acc.z; o.w += acc.w;
            *reinterpret_cast<float4*>(op) = o;
        } else {
            unsafeAtomicAdd(op + 0, acc.x);
            unsafeAtomicAdd(op + 1, acc.y);
            unsafeAtomicAdd(op + 2, acc.z);
            unsafeAtomicAdd(op + 3, acc.w);
        }
    }

    // ---- overflow edges, grid-stride over 32-lane groups ----
    int n_ovf = hdr[1];
    for (int i = gid >> 5; i < n_ovf; i += ngroups) {
        int2 sd = ovf[i];
        ushort4 y = *reinterpret_cast<const ushort4*>(
            Ybf + (size_t)sd.x * DF + lane * 4);
        float* op = out + (size_t)sd.y * DF + lane * 4;
        unsafeAtomicAdd(op + 0, bf2f(y.x));
        unsafeAtomicAdd(op + 1, bf2f(y.y));
        unsafeAtomicAdd(op + 2, bf2f(y.z));
        unsafeAtomicAdd(op + 3, bf2f(y.w));
    }
}

extern "C" void kernel_launch(void* const* d_in, const int* in_sizes, int n_in,
                              void* d_out, int out_size, void* d_ws, size_t ws_size,
                              hipStream_t stream) {
    const float* feat = (const float*)d_in[0];
    const void*  src  = d_in[1];
    const void*  dst  = d_in[2];
    const float* Wn   = (const float*)d_in[3];
    const float* bias = (const float*)d_in[4];
    const float* Wsf  = (const float*)d_in[5];
    float* out = (float*)d_out;

    const int M  = in_sizes[0] / DF;   // 100000
    const int nE = in_sizes[1];        // 600000

    // workspace: [hdr 256B][counts][buckets][Bt 64KB][Ybf][ovf]
    const size_t cnt_off   = 256;
    const size_t cnt_bytes = (((size_t)(M + 1) * 4) + 255) & ~(size_t)255;
    const size_t bkt_off   = cnt_off + cnt_bytes;
    const size_t bkt_bytes = (size_t)M * CAP * sizeof(int);
    const size_t bt_off    = (bkt_off + bkt_bytes + 255) & ~(size_t)255;
    const size_t bt_bytes  = (size_t)256 * DF * sizeof(unsigned short);
    const size_t y_off     = bt_off + bt_bytes;
    const size_t y_bytes   = (size_t)M * DF * sizeof(unsigned short);
    const size_t ovf_off   = (y_off + y_bytes + 255) & ~(size_t)255;

    int*            hdr     = (int*)d_ws;
    int*            counts  = (int*)((char*)d_ws + cnt_off);
    int*            buckets = (int*)((char*)d_ws + bkt_off);
    unsigned short* Bt      = (unsigned short*)((char*)d_ws + bt_off);
    unsigned short* Ybf     = (unsigned short*)((char*)d_ws + y_off);
    int2*           ovf     = (int2*)((char*)d_ws + ovf_off);

    const int cnt_ints = (int)(cnt_bytes / 4);
    const int nzb = (cnt_ints + 1023) / 1024;
    prep_kernel<<<1 + 128 + nzb, 256, 0, stream>>>(
        (const int*)src, nE, hdr, Wn, Wsf, Bt, counts, cnt_ints);

    const int gemm_blocks = (M + GR - 1) / GR;
    fused_kernel<<<PBLK + gemm_blocks, 256, 0, stream>>>(
        feat, Bt, bias, Ybf, out, M, src, dst, nE,
        hdr, counts, buckets, ovf);

    const int gablocks = (int)(((long long)M * 32 + 255) / 256);
    const int ngroups = gablocks * 8;
    gather_kernel<<<gablocks, 256, 0, stream>>>(
        Ybf, counts, buckets, hdr, ovf, out, M, ngroups);
}